// Round 8
// baseline (269.828 us; speedup 1.0000x reference)
//
#include <hip/hip_runtime.h>
#include <math.h>

// Round 8: back to safe multi-dispatch (rounds 6/7 grid-sync both failed on
// this platform). 4 dispatches:
//   prep: x fp32->f16 + W^T converts
//   qkv:  relu(x@W{q,k,v}+b), fused, 128x128 tiles (768 blocks)
//   mid:  E = QK^T/32 (triangular, writes -3000 sentinel for col>row)
//         || VWT = (V@Wo)^T           (1056 blocks)
//   pv:   out = relu(softmax(E)@VW + bo) with PER-BLOCK fused softmax:
//         pre-pass computes row max/sum from raw E (sentinels make masking
//         automatic), k-loop exponentiates A-frags on the fly. No grid sync.

typedef _Float16 f16x8 __attribute__((ext_vector_type(8)));
typedef float f32x4 __attribute__((ext_vector_type(4)));

#define BK 32   // halves per LDS row (64 B)

__device__ __forceinline__ void gload_lds16(const void* g, void* l) {
  __builtin_amdgcn_global_load_lds(
      (const __attribute__((address_space(1))) void*)g,
      (__attribute__((address_space(3))) void*)l, 16, 0, 0);
}

// Accumulate C-tile (m0,n0) of A @ BT^T over k < kend. LDS chunks of 8 halves;
// logical chunk c of row r at phys slot c ^ ((r>>1)&3) (zero bank conflicts);
// swizzle applied on the global-source side of global_load_lds.
template<int TMp, int TNp>
__device__ __forceinline__ void gemm_acc(
    const _Float16* __restrict__ A, const _Float16* __restrict__ BT,
    _Float16* Ah, _Float16* Bh, int sAr, int sBr, int kend, int m0, int n0,
    f32x4 (&acc)[TMp / 32][TNp / 32])
{
  const int tid  = threadIdx.x;
  const int lane = tid & 63;
  const int wid  = tid >> 6;
  const int wm   = (wid >> 1) * (TMp / 2);
  const int wn   = (wid & 1) * (TNp / 2);
  const int l15  = lane & 15;
  const int quad = lane >> 4;
  constexpr int MT = TMp / 32;
  constexpr int NT = TNp / 32;
  constexpr int AI = TMp / 64;
  constexpr int BI = TNp / 64;
  const int r16 = lane >> 2;
  const int swc = ((lane & 3) ^ ((lane >> 3) & 3)) * 8;
  const int arow = wid * (TMp / 4);
  const int brow = wid * (TNp / 4);

  for (int k0 = 0; k0 < kend; k0 += BK) {
    #pragma unroll
    for (int t = 0; t < AI; ++t)
      gload_lds16(A + (long long)(m0 + arow + t * 16 + r16) * sAr + k0 + swc,
                  Ah + (arow + t * 16) * BK);
    #pragma unroll
    for (int t = 0; t < BI; ++t)
      gload_lds16(BT + (long long)(n0 + brow + t * 16 + r16) * sBr + k0 + swc,
                  Bh + (brow + t * 16) * BK);
    __syncthreads();

    const int ch = (quad ^ ((l15 >> 1) & 3)) * 8;
    const _Float16* ab = Ah + (wm + l15) * BK + ch;
    const _Float16* bb = Bh + (wn + l15) * BK + ch;
    f16x8 af[MT], bf[NT];
    #pragma unroll
    for (int t = 0; t < MT; ++t) af[t] = *(const f16x8*)(ab + t * 16 * BK);
    #pragma unroll
    for (int t = 0; t < NT; ++t) bf[t] = *(const f16x8*)(bb + t * 16 * BK);
    #pragma unroll
    for (int mt = 0; mt < MT; ++mt)
      #pragma unroll
      for (int nt = 0; nt < NT; ++nt)
        acc[mt][nt] = __builtin_amdgcn_mfma_f32_16x16x32_f16(
            af[mt], bf[nt], acc[mt][nt], 0, 0, 0);
    __syncthreads();
  }
}

// Epilogue. C/D layout: col = lane&15, row = quad*4 + reg (HW-verified).
// CMASK: write -3000 sentinel where col > row (causal; exp -> exact 0 later).
template<int TMp, int TNp, bool RELU, bool HAS_BIAS, bool CMASK, typename OT>
__device__ __forceinline__ void gemm_store(
    f32x4 (&acc)[TMp / 32][TNp / 32], const float* __restrict__ bias,
    OT* __restrict__ C, int Nout, float scale, int m0, int n0)
{
  const int tid  = threadIdx.x;
  const int lane = tid & 63;
  const int wid  = tid >> 6;
  const int wm   = (wid >> 1) * (TMp / 2);
  const int wn   = (wid & 1) * (TNp / 2);
  const int l15  = lane & 15;
  const int quad = lane >> 4;
  constexpr int MT = TMp / 32;
  constexpr int NT = TNp / 32;

  float bvals[NT];
  if (HAS_BIAS) {
    #pragma unroll
    for (int nt = 0; nt < NT; ++nt)
      bvals[nt] = bias[n0 + wn + nt * 16 + l15];
  }
  #pragma unroll
  for (int mt = 0; mt < MT; ++mt) {
    #pragma unroll
    for (int nt = 0; nt < NT; ++nt) {
      const int col = n0 + wn + nt * 16 + l15;
      #pragma unroll
      for (int r = 0; r < 4; ++r) {
        const int row = m0 + wm + mt * 16 + quad * 4 + r;
        float v = acc[mt][nt][r] * scale;
        if (HAS_BIAS) v += bvals[nt];
        if (RELU) v = fmaxf(v, 0.f);
        if (CMASK && col > row) v = -3000.0f;
        C[(long long)row * Nout + col] = (OT)v;
      }
    }
  }
}

// fused QKV: relu(x @ W{q,k,v} + b) -> f16; Wcat = [Wq^T;Wk^T;Wv^T;Wo^T]
__global__ __launch_bounds__(256) void qkv_kernel(
    const _Float16* __restrict__ xh, const _Float16* __restrict__ Wcat,
    const float* __restrict__ bq, const float* __restrict__ bk,
    const float* __restrict__ bv,
    _Float16* __restrict__ Qh, _Float16* __restrict__ Kh,
    _Float16* __restrict__ Vh, int D)
{
  __shared__ _Float16 Ah[128 * BK];
  __shared__ _Float16 Bh[128 * BK];
  const int m0  = blockIdx.y * 128;
  const int n0g = blockIdx.x * 128;       // 0..3071
  f32x4 acc[4][4];
  #pragma unroll
  for (int i = 0; i < 4; ++i)
    #pragma unroll
    for (int j = 0; j < 4; ++j) acc[i][j] = (f32x4){0.f, 0.f, 0.f, 0.f};

  gemm_acc<128, 128>(xh, Wcat, Ah, Bh, D, D, D, m0, n0g, acc);

  const int mat = n0g >> 10;              // D = 1024
  const int c0  = n0g & 1023;
  _Float16* C = (mat == 0) ? Qh : (mat == 1) ? Kh : Vh;
  const float* bias = (mat == 0) ? bq : (mat == 1) ? bk : bv;
  gemm_store<128, 128, true, true, false, _Float16>(acc, bias, C, D, 1.0f, m0, c0);
}

// mid: blocks 0..543 -> E = QK^T/32 (triangular, TM=128,TN=64, causal
// sentinel); blocks 544..1055 -> VWT = (V@Wo)^T.
__global__ __launch_bounds__(256) void mid_kernel(
    const _Float16* __restrict__ Qh, const _Float16* __restrict__ Kh,
    _Float16* __restrict__ E, const _Float16* __restrict__ WoT,
    const _Float16* __restrict__ Vh, _Float16* __restrict__ VWT,
    int S, int D)
{
  __shared__ _Float16 Ah[128 * BK];
  __shared__ _Float16 Bh[64 * BK];
  const int id = blockIdx.x;
  f32x4 acc[4][2];
  #pragma unroll
  for (int i = 0; i < 4; ++i)
    #pragma unroll
    for (int j = 0; j < 2; ++j) acc[i][j] = (f32x4){0.f, 0.f, 0.f, 0.f};

  if (id < 544) {                          // QK^T, 272 tiles per batch
    const int z = (id >= 272);
    const int t = id - z * 272;
    int i = (int)((sqrtf(4.f * t + 1.f) - 1.f) * 0.5f);
    while ((i + 1) * (i + 2) <= t) ++i;
    while (i * (i + 1) > t) --i;
    const int j = t - i * (i + 1);         // 0..2i+1
    const int m0 = i * 128, n0 = j * 64;
    gemm_acc<128, 64>(Qh + (long long)z * S * D, Kh + (long long)z * S * D,
                      Ah, Bh, D, D, D, m0, n0, acc);
    gemm_store<128, 64, false, false, true, _Float16>(
        acc, nullptr, E + (long long)z * S * S, S, 0.03125f, m0, n0);
  } else {                                 // V @ Wo, 256 tiles per batch
    const int t = id - 544;
    const int z = t >> 8;
    const int u = t & 255;
    const int m0 = (u >> 5) * 128;         // D rows of Wo^T
    const int n0 = (u & 31) * 64;          // S cols (V rows)
    gemm_acc<128, 64>(WoT, Vh + (long long)z * S * D,
                      Ah, Bh, D, D, D, m0, n0, acc);
    gemm_store<128, 64, false, false, false, _Float16>(
        acc, nullptr, VWT + (long long)z * D * S, S, 1.0f, m0, n0);
  }
}

// out = relu(softmax(E) @ VW + bo); softmax fused per-block:
// pre-pass computes (max, 1/sum) for this block's 64 rows from raw E
// (sentinels -3000 make causal masking automatic), k-loop exponentiates
// A-frags on the fly. kend = m0+64. Heavy tiles dispatch first.
__global__ __launch_bounds__(256) void pv_kernel(
    const _Float16* __restrict__ E, const _Float16* __restrict__ VWT,
    const float* __restrict__ bo, float* __restrict__ out, int S, int D)
{
  __shared__ _Float16 Ah[64 * BK];
  __shared__ _Float16 Bh[128 * BK];
  __shared__ float rowinfo[128];           // (max, inv_sum) per row
  const int z  = blockIdx.z;
  const int m0 = ((int)gridDim.y - 1 - (int)blockIdx.y) * 64;
  const int n0 = blockIdx.x * 128;
  const _Float16* Eb = E + (long long)z * S * S;
  const _Float16* BT = VWT + (long long)z * D * S;
  float* C = out + (long long)z * S * D;
  const int kend = m0 + 64;

  // ---- pre-pass: row max then sum(exp) over j in [0,kend), 4 lanes/row ----
  const int tid = threadIdx.x;
  {
    const int r = tid >> 2;                // 0..63
    const int c = tid & 3;
    const _Float16* rowp = Eb + (long long)(m0 + r) * S;
    float mx = -3.0e38f;
    for (int j = c * 8; j < kend; j += 32) {
      f16x8 v = *(const f16x8*)(rowp + j);
      #pragma unroll
      for (int t = 0; t < 8; ++t) mx = fmaxf(mx, (float)v[t]);
    }
    mx = fmaxf(mx, __shfl_xor(mx, 1, 64));
    mx = fmaxf(mx, __shfl_xor(mx, 2, 64));
    float sm = 0.f;
    for (int j = c * 8; j < kend; j += 32) {
      f16x8 v = *(const f16x8*)(rowp + j);
      #pragma unroll
      for (int t = 0; t < 8; ++t) sm += __expf((float)v[t] - mx);
    }
    sm += __shfl_xor(sm, 1, 64);
    sm += __shfl_xor(sm, 2, 64);
    if (c == 0) { rowinfo[r * 2] = mx; rowinfo[r * 2 + 1] = 1.0f / sm; }
  }
  __syncthreads();

  const int lane = tid & 63;
  const int wid  = tid >> 6;
  const int wm   = (wid >> 1) * 32;        // TMp/2
  const int wn   = (wid & 1) * 64;         // TNp/2
  const int l15  = lane & 15;
  const int quad = lane >> 4;

  float mrow[2], il[2];
  #pragma unroll
  for (int mt = 0; mt < 2; ++mt) {
    const int rl = wm + mt * 16 + l15;
    mrow[mt] = rowinfo[rl * 2];
    il[mt]   = rowinfo[rl * 2 + 1];
  }

  f32x4 acc[2][4];
  #pragma unroll
  for (int a = 0; a < 2; ++a)
    #pragma unroll
    for (int b = 0; b < 4; ++b) acc[a][b] = (f32x4){0.f, 0.f, 0.f, 0.f};

  const int r16 = lane >> 2;
  const int swc = ((lane & 3) ^ ((lane >> 3) & 3)) * 8;
  const int arow = wid * 16;               // TMp/4
  const int brow = wid * 32;               // TNp/4

  for (int k0 = 0; k0 < kend; k0 += BK) {
    gload_lds16(Eb + (long long)(m0 + arow + r16) * S + k0 + swc,
                Ah + arow * BK);
    #pragma unroll
    for (int t = 0; t < 2; ++t)
      gload_lds16(BT + (long long)(n0 + brow + t * 16 + r16) * S + k0 + swc,
                  Bh + (brow + t * 16) * BK);
    __syncthreads();

    const int ch = (quad ^ ((l15 >> 1) & 3)) * 8;
    const _Float16* ab = Ah + (wm + l15) * BK + ch;
    const _Float16* bb = Bh + (wn + l15) * BK + ch;
    f16x8 af[2], bf[4];
    #pragma unroll
    for (int t = 0; t < 2; ++t) af[t] = *(const f16x8*)(ab + t * 16 * BK);
    // on-the-fly softmax: p = exp(e - m_row) * inv_sum  (sentinels -> 0)
    #pragma unroll
    for (int mt = 0; mt < 2; ++mt) {
      f16x8 p;
      #pragma unroll
      for (int e = 0; e < 8; ++e)
        p[e] = (_Float16)(__expf((float)af[mt][e] - mrow[mt]) * il[mt]);
      af[mt] = p;
    }
    #pragma unroll
    for (int t = 0; t < 4; ++t) bf[t] = *(const f16x8*)(bb + t * 16 * BK);
    #pragma unroll
    for (int mt = 0; mt < 2; ++mt)
      #pragma unroll
      for (int nt = 0; nt < 4; ++nt)
        acc[mt][nt] = __builtin_amdgcn_mfma_f32_16x16x32_f16(
            af[mt], bf[nt], acc[mt][nt], 0, 0, 0);
    __syncthreads();
  }

  gemm_store<64, 128, true, true, false, float>(acc, bo, C, D, 1.0f, m0, n0);
}

// prep: blocks 0..2047 = x fp32->f16; 2048..3071 = W transpose+convert.
__global__ __launch_bounds__(256) void prep_kernel(
    const float* __restrict__ x, _Float16* __restrict__ xh,
    const float* __restrict__ W0, const float* __restrict__ W1,
    const float* __restrict__ W2, const float* __restrict__ W3,
    _Float16* __restrict__ Wcat, int D)
{
  const int id = blockIdx.x;
  const int tid = threadIdx.x;
  if (id < 2048) {
    const long long i = ((long long)id * 256 + tid) * 8;
    float4 a = *(const float4*)(x + i);
    float4 b = *(const float4*)(x + i + 4);
    f16x8 o = {(_Float16)a.x, (_Float16)a.y, (_Float16)a.z, (_Float16)a.w,
               (_Float16)b.x, (_Float16)b.y, (_Float16)b.z, (_Float16)b.w};
    *(f16x8*)(xh + i) = o;
    return;
  }
  __shared__ _Float16 t[64][72];
  const int u = id - 2048;
  const int z = u >> 8;
  const int v = u & 255;
  const float* W = (z == 0) ? W0 : (z == 1) ? W1 : (z == 2) ? W2 : W3;
  _Float16* dst = Wcat + (long long)z * D * D;
  const int k0 = (v >> 4) * 64, n0 = (v & 15) * 64;
  #pragma unroll
  for (int it = 0; it < 4; ++it) {
    int idx = tid + it * 256;
    int r = idx >> 4, c4 = (idx & 15) << 2;
    float4 w = *(const float4*)(W + (long long)(k0 + r) * D + n0 + c4);
    t[r][c4 + 0] = (_Float16)w.x; t[r][c4 + 1] = (_Float16)w.y;
    t[r][c4 + 2] = (_Float16)w.z; t[r][c4 + 3] = (_Float16)w.w;
  }
  __syncthreads();
  #pragma unroll
  for (int it = 0; it < 2; ++it) {
    int idx = tid + it * 256;
    int r = idx >> 3, c8 = (idx & 7) << 3;
    f16x8 o;
    #pragma unroll
    for (int j = 0; j < 8; ++j) o[j] = t[c8 + j][r];
    *(f16x8*)(dst + (long long)(n0 + r) * D + k0 + c8) = o;
  }
}

extern "C" void kernel_launch(void* const* d_in, const int* in_sizes, int n_in,
                              void* d_out, int out_size, void* d_ws, size_t ws_size,
                              hipStream_t stream) {
  const float* x  = (const float*)d_in[0];
  const float* Wq = (const float*)d_in[1];
  const float* bq = (const float*)d_in[2];
  const float* Wk = (const float*)d_in[3];
  const float* bk = (const float*)d_in[4];
  const float* Wv = (const float*)d_in[5];
  const float* bv = (const float*)d_in[6];
  const float* Wo = (const float*)d_in[7];
  const float* bo = (const float*)d_in[8];
  float* out = (float*)d_out;

  const int Bn = 2, S = 2048, D = 1024;
  const int M = Bn * S;                       // 4096
  const size_t MD = (size_t)M * D;            // 4M elems
  const size_t DD = (size_t)D * D;            // 1M
  const size_t SS = (size_t)Bn * S * S;       // 8M

  _Float16* ws   = (_Float16*)d_ws;
  _Float16* xh   = ws;                 // MD
  _Float16* Wcat = xh + MD;            // 4*DD
  _Float16* Qh   = Wcat + 4 * DD;      // MD
  _Float16* Kh   = Qh + MD;            // MD
  _Float16* Vh   = Kh + MD;            // MD
  _Float16* VWT  = Vh + MD;            // MD  ((V@Wo)^T, [D,S] per batch)
  _Float16* E    = VWT + MD;           // SS  (raw scaled scores + sentinels)

  dim3 blk(256);

  prep_kernel<<<dim3(3072), blk, 0, stream>>>(x, xh, Wq, Wk, Wv, Wo, Wcat, D);

  qkv_kernel<<<dim3(3 * D / 128, M / 128), blk, 0, stream>>>(
      xh, Wcat, bq, bk, bv, Qh, Kh, Vh, D);

  mid_kernel<<<dim3(1056), blk, 0, stream>>>(
      Qh, Kh, E, Wcat + 3 * DD, Vh, VWT, S, D);

  pv_kernel<<<dim3(D / 128, S / 64, Bn), blk, 0, stream>>>(
      E, VWT, bo, out, S, D);
}

// Round 10
// 218.318 us; speedup vs baseline: 1.2359x; 1.2359x over previous
//
#include <hip/hip_runtime.h>
#include <math.h>

// Round 10 = round-9 resubmitted verbatim (r9 bench died to container infra
// flake, not kernel: no spin/coop-launch, all indices audited in-bounds).
// Structure: round-5 (best passing 208.8 µs) with mid restructured:
//   QK^T at 128x128 tiles (272 triangular blocks; 2x MFMA per staged byte)
//   + V@Wo at 128x64 (512 blocks) = 784 blocks (~3/CU).
// 5 dispatches: prep, qkv, mid, softmax, pv. No grid sync (r6/r7 both died).
// Round-8 lesson: do NOT fuse softmax into pv (redundant stats + in-loop exp
// is VALU-bound, 4x slower).

typedef _Float16 f16x8 __attribute__((ext_vector_type(8)));
typedef float f32x4 __attribute__((ext_vector_type(4)));

#define BK 32   // halves per LDS row (64 B)

__device__ __forceinline__ void gload_lds16(const void* g, void* l) {
  __builtin_amdgcn_global_load_lds(
      (const __attribute__((address_space(1))) void*)g,
      (__attribute__((address_space(3))) void*)l, 16, 0, 0);
}

// Accumulate C-tile (m0,n0) of A @ BT^T over k < kend. LDS chunks of 8 halves;
// logical chunk c of row r at phys slot c ^ ((r>>1)&3) (zero bank conflicts);
// swizzle applied on the global-source side of global_load_lds.
template<int TMp, int TNp>
__device__ __forceinline__ void gemm_acc(
    const _Float16* __restrict__ A, const _Float16* __restrict__ BT,
    _Float16* Ah, _Float16* Bh, int sAr, int sBr, int kend, int m0, int n0,
    f32x4 (&acc)[TMp / 32][TNp / 32])
{
  const int tid  = threadIdx.x;
  const int lane = tid & 63;
  const int wid  = tid >> 6;
  const int wm   = (wid >> 1) * (TMp / 2);
  const int wn   = (wid & 1) * (TNp / 2);
  const int l15  = lane & 15;
  const int quad = lane >> 4;
  constexpr int MT = TMp / 32;
  constexpr int NT = TNp / 32;
  constexpr int AI = TMp / 64;
  constexpr int BI = TNp / 64;
  const int r16 = lane >> 2;
  const int swc = ((lane & 3) ^ ((lane >> 3) & 3)) * 8;
  const int arow = wid * (TMp / 4);
  const int brow = wid * (TNp / 4);

  for (int k0 = 0; k0 < kend; k0 += BK) {
    #pragma unroll
    for (int t = 0; t < AI; ++t)
      gload_lds16(A + (long long)(m0 + arow + t * 16 + r16) * sAr + k0 + swc,
                  Ah + (arow + t * 16) * BK);
    #pragma unroll
    for (int t = 0; t < BI; ++t)
      gload_lds16(BT + (long long)(n0 + brow + t * 16 + r16) * sBr + k0 + swc,
                  Bh + (brow + t * 16) * BK);
    __syncthreads();

    const int ch = (quad ^ ((l15 >> 1) & 3)) * 8;
    const _Float16* ab = Ah + (wm + l15) * BK + ch;
    const _Float16* bb = Bh + (wn + l15) * BK + ch;
    f16x8 af[MT], bf[NT];
    #pragma unroll
    for (int t = 0; t < MT; ++t) af[t] = *(const f16x8*)(ab + t * 16 * BK);
    #pragma unroll
    for (int t = 0; t < NT; ++t) bf[t] = *(const f16x8*)(bb + t * 16 * BK);
    #pragma unroll
    for (int mt = 0; mt < MT; ++mt)
      #pragma unroll
      for (int nt = 0; nt < NT; ++nt)
        acc[mt][nt] = __builtin_amdgcn_mfma_f32_16x16x32_f16(
            af[mt], bf[nt], acc[mt][nt], 0, 0, 0);
    __syncthreads();
  }
}

// Epilogue. C/D layout: col = lane&15, row = quad*4 + reg (HW-verified).
template<int TMp, int TNp, bool RELU, bool HAS_BIAS, typename OT>
__device__ __forceinline__ void gemm_store(
    f32x4 (&acc)[TMp / 32][TNp / 32], const float* __restrict__ bias,
    OT* __restrict__ C, int Nout, float scale, int m0, int n0)
{
  const int tid  = threadIdx.x;
  const int lane = tid & 63;
  const int wid  = tid >> 6;
  const int wm   = (wid >> 1) * (TMp / 2);
  const int wn   = (wid & 1) * (TNp / 2);
  const int l15  = lane & 15;
  const int quad = lane >> 4;
  constexpr int MT = TMp / 32;
  constexpr int NT = TNp / 32;

  float bvals[NT];
  if (HAS_BIAS) {
    #pragma unroll
    for (int nt = 0; nt < NT; ++nt)
      bvals[nt] = bias[n0 + wn + nt * 16 + l15];
  }
  #pragma unroll
  for (int mt = 0; mt < MT; ++mt) {
    #pragma unroll
    for (int nt = 0; nt < NT; ++nt) {
      const int col = n0 + wn + nt * 16 + l15;
      #pragma unroll
      for (int r = 0; r < 4; ++r) {
        const int row = m0 + wm + mt * 16 + quad * 4 + r;
        float v = acc[mt][nt][r] * scale;
        if (HAS_BIAS) v += bvals[nt];
        if (RELU) v = fmaxf(v, 0.f);
        C[(long long)row * Nout + col] = (OT)v;
      }
    }
  }
}

// fused QKV: relu(x @ W{q,k,v} + b) -> f16; Wcat = [Wq^T;Wk^T;Wv^T;Wo^T]
__global__ __launch_bounds__(256) void qkv_kernel(
    const _Float16* __restrict__ xh, const _Float16* __restrict__ Wcat,
    const float* __restrict__ bq, const float* __restrict__ bk,
    const float* __restrict__ bv,
    _Float16* __restrict__ Qh, _Float16* __restrict__ Kh,
    _Float16* __restrict__ Vh, int D)
{
  __shared__ _Float16 Ah[128 * BK];
  __shared__ _Float16 Bh[128 * BK];
  const int m0  = blockIdx.y * 128;
  const int n0g = blockIdx.x * 128;       // 0..3071
  f32x4 acc[4][4];
  #pragma unroll
  for (int i = 0; i < 4; ++i)
    #pragma unroll
    for (int j = 0; j < 4; ++j) acc[i][j] = (f32x4){0.f, 0.f, 0.f, 0.f};

  gemm_acc<128, 128>(xh, Wcat, Ah, Bh, D, D, D, m0, n0g, acc);

  const int mat = n0g >> 10;              // D = 1024
  const int c0  = n0g & 1023;
  _Float16* C = (mat == 0) ? Qh : (mat == 1) ? Kh : Vh;
  const float* bias = (mat == 0) ? bq : (mat == 1) ? bk : bv;
  gemm_store<128, 128, true, true, _Float16>(acc, bias, C, D, 1.0f, m0, c0);
}

// mid: blocks 0..271   -> E = QK^T/32, 128x128 triangular tiles (136/batch);
//      blocks 272..783 -> VWT = (V@Wo)^T, 128x64 tiles (256/batch).
__global__ __launch_bounds__(256) void mid_kernel(
    const _Float16* __restrict__ Qh, const _Float16* __restrict__ Kh,
    _Float16* __restrict__ E, const _Float16* __restrict__ WoT,
    const _Float16* __restrict__ Vh, _Float16* __restrict__ VWT,
    int S, int D)
{
  __shared__ _Float16 Ah[128 * BK];
  __shared__ _Float16 Bh[128 * BK];
  const int id = blockIdx.x;
  if (id < 272) {                          // QK^T, 136 tiles per batch (j<=i)
    const int z = (id >= 136);
    const int t = id - z * 136;
    int i = (int)((sqrtf(8.f * t + 1.f) - 1.f) * 0.5f);
    while ((i + 1) * (i + 2) / 2 <= t) ++i;
    while (i * (i + 1) / 2 > t) --i;
    const int j = t - i * (i + 1) / 2;     // 0..i
    const int m0 = i * 128, n0 = j * 128;
    f32x4 acc[4][4];
    #pragma unroll
    for (int a = 0; a < 4; ++a)
      #pragma unroll
      for (int b = 0; b < 4; ++b) acc[a][b] = (f32x4){0.f, 0.f, 0.f, 0.f};
    gemm_acc<128, 128>(Qh + (long long)z * S * D, Kh + (long long)z * S * D,
                       Ah, Bh, D, D, D, m0, n0, acc);
    gemm_store<128, 128, false, false, _Float16>(
        acc, nullptr, E + (long long)z * S * S, S, 0.03125f, m0, n0);
  } else {                                 // V @ Wo, 256 tiles per batch
    const int t = id - 272;
    const int z = t >> 8;
    const int u = t & 255;
    const int m0 = (u >> 5) * 128;         // D rows of Wo^T
    const int n0 = (u & 31) * 64;          // S cols (V rows)
    f32x4 acc[4][2];
    #pragma unroll
    for (int a = 0; a < 4; ++a)
      #pragma unroll
      for (int b = 0; b < 2; ++b) acc[a][b] = (f32x4){0.f, 0.f, 0.f, 0.f};
    gemm_acc<128, 64>(WoT, Vh + (long long)z * S * D,
                      Ah, Bh, D, D, D, m0, n0, acc);
    gemm_store<128, 64, false, false, _Float16>(
        acc, nullptr, VWT + (long long)z * D * S, S, 1.0f, m0, n0);
  }
}

// out = relu(P @ VW + bo) -> fp32; kend = m0+64 (causal cap); heavy tiles first
__global__ __launch_bounds__(256) void pv_kernel(
    const _Float16* __restrict__ E, const _Float16* __restrict__ VWT,
    const float* __restrict__ bo, float* __restrict__ out, int S, int D)
{
  __shared__ _Float16 Ah[64 * BK];
  __shared__ _Float16 Bh[128 * BK];
  const int z  = blockIdx.z;
  const int m0 = ((int)gridDim.y - 1 - (int)blockIdx.y) * 64;
  const int n0 = blockIdx.x * 128;
  const _Float16* A  = E + (long long)z * S * S;
  const _Float16* BT = VWT + (long long)z * D * S;
  float* C = out + (long long)z * S * D;
  const int kend = m0 + 64;

  f32x4 acc[2][4];
  #pragma unroll
  for (int i = 0; i < 2; ++i)
    #pragma unroll
    for (int j = 0; j < 4; ++j) acc[i][j] = (f32x4){0.f, 0.f, 0.f, 0.f};

  gemm_acc<64, 128>(A, BT, Ah, Bh, S, S, kend, m0, n0, acc);
  gemm_store<64, 128, true, true, float>(acc, bo, C, D, 1.0f, m0, n0);
}

// prep: blocks 0..2047 = x fp32->f16 (8 elems/thread);
//       blocks 2048..3071 = W transpose+convert into Wcat (64x64 tiles)
__global__ __launch_bounds__(256) void prep_kernel(
    const float* __restrict__ x, _Float16* __restrict__ xh,
    const float* __restrict__ W0, const float* __restrict__ W1,
    const float* __restrict__ W2, const float* __restrict__ W3,
    _Float16* __restrict__ Wcat, int D)
{
  const int id = blockIdx.x;
  const int tid = threadIdx.x;
  if (id < 2048) {
    const long long i = ((long long)id * 256 + tid) * 8;
    float4 a = *(const float4*)(x + i);
    float4 b = *(const float4*)(x + i + 4);
    f16x8 o = {(_Float16)a.x, (_Float16)a.y, (_Float16)a.z, (_Float16)a.w,
               (_Float16)b.x, (_Float16)b.y, (_Float16)b.z, (_Float16)b.w};
    *(f16x8*)(xh + i) = o;
    return;
  }
  __shared__ _Float16 t[64][72];
  const int u = id - 2048;
  const int z = u >> 8;
  const int v = u & 255;
  const float* W = (z == 0) ? W0 : (z == 1) ? W1 : (z == 2) ? W2 : W3;
  _Float16* dst = Wcat + (long long)z * D * D;
  const int k0 = (v >> 4) * 64, n0 = (v & 15) * 64;
  #pragma unroll
  for (int it = 0; it < 4; ++it) {
    int idx = tid + it * 256;
    int r = idx >> 4, c4 = (idx & 15) << 2;
    float4 w = *(const float4*)(W + (long long)(k0 + r) * D + n0 + c4);
    t[r][c4 + 0] = (_Float16)w.x; t[r][c4 + 1] = (_Float16)w.y;
    t[r][c4 + 2] = (_Float16)w.z; t[r][c4 + 3] = (_Float16)w.w;
  }
  __syncthreads();
  #pragma unroll
  for (int it = 0; it < 2; ++it) {
    int idx = tid + it * 256;
    int r = idx >> 3, c8 = (idx & 7) << 3;
    f16x8 o;
    #pragma unroll
    for (int j = 0; j < 8; ++j) o[j] = t[c8 + j][r];
    *(f16x8*)(dst + (long long)(n0 + r) * D + k0 + c8) = o;
  }
}

// in-place causal softmax, fp32 math, f16 IO; zeros for j > i
__global__ __launch_bounds__(256) void softmax_causal_h(
    _Float16* __restrict__ E, int S)
{
  const int i = blockIdx.x;
  _Float16* row = E + ((long long)blockIdx.y * S + i) * S;
  const int tid = threadIdx.x;
  const int n = i + 1;
  const int j0 = tid * 8;

  f16x8 hv = *(const f16x8*)(row + j0);
  float vals[8];
  float m = -3.0e38f;
  #pragma unroll
  for (int t = 0; t < 8; ++t) {
    float v = (j0 + t < n) ? (float)hv[t] : -3.0e38f;
    vals[t] = v;
    m = fmaxf(m, v);
  }
  #pragma unroll
  for (int o = 32; o > 0; o >>= 1) m = fmaxf(m, __shfl_down(m, o, 64));

  __shared__ float rmax[4];
  __shared__ float rsum[4];
  const int wave = tid >> 6;
  if ((tid & 63) == 0) rmax[wave] = m;
  __syncthreads();
  m = fmaxf(fmaxf(rmax[0], rmax[1]), fmaxf(rmax[2], rmax[3]));

  float s = 0.f;
  #pragma unroll
  for (int t = 0; t < 8; ++t) {
    float e = (j0 + t < n) ? expf(vals[t] - m) : 0.f;
    vals[t] = e;
    s += e;
  }
  #pragma unroll
  for (int o = 32; o > 0; o >>= 1) s += __shfl_down(s, o, 64);
  if ((tid & 63) == 0) rsum[wave] = s;
  __syncthreads();
  s = rsum[0] + rsum[1] + rsum[2] + rsum[3];

  const float inv = 1.0f / s;
  f16x8 ov;
  #pragma unroll
  for (int t = 0; t < 8; ++t) ov[t] = (_Float16)(vals[t] * inv);
  *(f16x8*)(row + j0) = ov;
}

extern "C" void kernel_launch(void* const* d_in, const int* in_sizes, int n_in,
                              void* d_out, int out_size, void* d_ws, size_t ws_size,
                              hipStream_t stream) {
  const float* x  = (const float*)d_in[0];
  const float* Wq = (const float*)d_in[1];
  const float* bq = (const float*)d_in[2];
  const float* Wk = (const float*)d_in[3];
  const float* bk = (const float*)d_in[4];
  const float* Wv = (const float*)d_in[5];
  const float* bv = (const float*)d_in[6];
  const float* Wo = (const float*)d_in[7];
  const float* bo = (const float*)d_in[8];
  float* out = (float*)d_out;

  const int Bn = 2, S = 2048, D = 1024;
  const int M = Bn * S;                       // 4096
  const size_t MD = (size_t)M * D;            // 4M elems
  const size_t DD = (size_t)D * D;            // 1M
  const size_t SS = (size_t)Bn * S * S;       // 8M

  _Float16* ws   = (_Float16*)d_ws;
  _Float16* xh   = ws;                 // MD
  _Float16* Wcat = xh + MD;            // 4*DD
  _Float16* Qh   = Wcat + 4 * DD;      // MD
  _Float16* Kh   = Qh + MD;            // MD
  _Float16* Vh   = Kh + MD;            // MD
  _Float16* VWT  = Vh + MD;            // MD  ((V@Wo)^T, [D,S] per batch)
  _Float16* E    = VWT + MD;           // SS

  dim3 blk(256);

  prep_kernel<<<dim3(3072), blk, 0, stream>>>(x, xh, Wq, Wk, Wv, Wo, Wcat, D);

  qkv_kernel<<<dim3(3 * D / 128, M / 128), blk, 0, stream>>>(
      xh, Wcat, bq, bk, bv, Qh, Kh, Vh, D);

  mid_kernel<<<dim3(784), blk, 0, stream>>>(
      Qh, Kh, E, Wcat + 3 * DD, Vh, VWT, S, D);

  softmax_causal_h<<<dim3(S, Bn), blk, 0, stream>>>(E, S);

  pv_kernel<<<dim3(D / 128, S / 64, Bn), blk, 0, stream>>>(
      E, VWT, bo, out, S, D);
}

// Round 12
// 213.035 us; speedup vs baseline: 1.2666x; 1.0248x over previous
//
#include <hip/hip_runtime.h>
#include <math.h>

// Round 12 = round-11 resubmitted verbatim (r11 bench died to container infra
// flake; code audited: no spin/coop-launch, LDS/global bounds verified, swizzle
// phase-minimal. Precedent: r9 flake -> r10 verbatim resubmit passed).
// Structure: round-5 (best passing 208.8 µs) with GEMM core swapped to
// mfma_f32_32x32x16_f16 (µbench 2382-2495 TF vs 2075-2176 for 16x16x32; half
// the MFMA instrs and half the ds_read issue pressure per FLOP). Same staging
// (BK=32, XOR swizzle, global_load_lds w16), fp32 accum. mid at round-5
// geometry (1056 uniform 128x64 tiles). 5 dispatches; no grid sync.

typedef _Float16 f16x8 __attribute__((ext_vector_type(8)));
typedef float f32x4 __attribute__((ext_vector_type(4)));
typedef float f32x16 __attribute__((ext_vector_type(16)));

#define BK 32   // halves per LDS row (64 B)

__device__ __forceinline__ void gload_lds16(const void* g, void* l) {
  __builtin_amdgcn_global_load_lds(
      (const __attribute__((address_space(1))) void*)g,
      (__attribute__((address_space(3))) void*)l, 16, 0, 0);
}

// Accumulate C-tile (m0,n0) of A @ BT^T over k < kend with 32x32x16 MFMA.
// Wave region (TMp/2 x TNp/2) as (TMp/64 x TNp/64) 32x32 tiles.
// LDS: [row][chunk] chunks of 8 halves; logical chunk c of row r at phys slot
// c ^ ((r>>1)&3); swizzle applied on the global-source side of
// global_load_lds and mirrored in ds_read.
// Operand maps (A and B symmetric => k-permutations cancel):
//   A[m=lane&31][k=8*(lane>>5)+j], B likewise with n in place of m.
template<int TMp, int TNp>
__device__ __forceinline__ void gemm_acc32(
    const _Float16* __restrict__ A, const _Float16* __restrict__ BT,
    _Float16* Ah, _Float16* Bh, int sAr, int sBr, int kend, int m0, int n0,
    f32x16 (&acc)[TMp / 64][TNp / 64])
{
  const int tid  = threadIdx.x;
  const int lane = tid & 63;
  const int wid  = tid >> 6;
  const int wm   = (wid >> 1) * (TMp / 2);
  const int wn   = (wid & 1) * (TNp / 2);
  const int l31  = lane & 31;
  const int hi   = lane >> 5;
  constexpr int MT = TMp / 64;
  constexpr int NT = TNp / 64;
  constexpr int AI = TMp / 64;            // staging instrs per wave
  constexpr int BI = TNp / 64;
  const int r16 = lane >> 2;
  const int swc = ((lane & 3) ^ ((lane >> 3) & 3)) * 8;
  const int arow = wid * (TMp / 4);
  const int brow = wid * (TNp / 4);
  const int s = (l31 >> 1) & 3;           // read-side swizzle key

  for (int k0 = 0; k0 < kend; k0 += BK) {
    #pragma unroll
    for (int t = 0; t < AI; ++t)
      gload_lds16(A + (long long)(m0 + arow + t * 16 + r16) * sAr + k0 + swc,
                  Ah + (arow + t * 16) * BK);
    #pragma unroll
    for (int t = 0; t < BI; ++t)
      gload_lds16(BT + (long long)(n0 + brow + t * 16 + r16) * sBr + k0 + swc,
                  Bh + (brow + t * 16) * BK);
    __syncthreads();

    #pragma unroll
    for (int ks = 0; ks < 2; ++ks) {
      const int ch = ((ks * 2 + hi) ^ s) * 8;   // swizzled slot
      f16x8 af[MT], bf[NT];
      #pragma unroll
      for (int mt = 0; mt < MT; ++mt)
        af[mt] = *(const f16x8*)(Ah + (wm + mt * 32 + l31) * BK + ch);
      #pragma unroll
      for (int nt = 0; nt < NT; ++nt)
        bf[nt] = *(const f16x8*)(Bh + (wn + nt * 32 + l31) * BK + ch);
      #pragma unroll
      for (int mt = 0; mt < MT; ++mt)
        #pragma unroll
        for (int nt = 0; nt < NT; ++nt)
          acc[mt][nt] = __builtin_amdgcn_mfma_f32_32x32x16_f16(
              af[mt], bf[nt], acc[mt][nt], 0, 0, 0);
    }
    __syncthreads();
  }
}

// Epilogue for 32x32 C/D (HW-verified m74/m101, dtype-independent):
//   col = lane&31, row = (reg&3) + 8*(reg>>2) + 4*(lane>>5).
template<int TMp, int TNp, bool RELU, bool HAS_BIAS, typename OT>
__device__ __forceinline__ void gemm_store32(
    f32x16 (&acc)[TMp / 64][TNp / 64], const float* __restrict__ bias,
    OT* __restrict__ C, int Nout, float scale, int m0, int n0)
{
  const int tid  = threadIdx.x;
  const int lane = tid & 63;
  const int wid  = tid >> 6;
  const int wm   = (wid >> 1) * (TMp / 2);
  const int wn   = (wid & 1) * (TNp / 2);
  const int l31  = lane & 31;
  const int hi   = lane >> 5;
  constexpr int MT = TMp / 64;
  constexpr int NT = TNp / 64;

  float bvals[NT];
  if (HAS_BIAS) {
    #pragma unroll
    for (int nt = 0; nt < NT; ++nt)
      bvals[nt] = bias[n0 + wn + nt * 32 + l31];
  }
  #pragma unroll
  for (int mt = 0; mt < MT; ++mt) {
    #pragma unroll
    for (int nt = 0; nt < NT; ++nt) {
      const int col = n0 + wn + nt * 32 + l31;
      const int rbase = m0 + wm + mt * 32 + 4 * hi;
      #pragma unroll
      for (int r = 0; r < 16; ++r) {
        const int row = rbase + (r & 3) + 8 * (r >> 2);
        float v = acc[mt][nt][r] * scale;
        if (HAS_BIAS) v += bvals[nt];
        if (RELU) v = fmaxf(v, 0.f);
        C[(long long)row * Nout + col] = (OT)v;
      }
    }
  }
}

// fused QKV: relu(x @ W{q,k,v} + b) -> f16; Wcat = [Wq^T;Wk^T;Wv^T;Wo^T]
__global__ __launch_bounds__(256) void qkv_kernel(
    const _Float16* __restrict__ xh, const _Float16* __restrict__ Wcat,
    const float* __restrict__ bq, const float* __restrict__ bk,
    const float* __restrict__ bv,
    _Float16* __restrict__ Qh, _Float16* __restrict__ Kh,
    _Float16* __restrict__ Vh, int D)
{
  __shared__ _Float16 Ah[128 * BK];
  __shared__ _Float16 Bh[128 * BK];
  const int m0  = blockIdx.y * 128;
  const int n0g = blockIdx.x * 128;       // 0..3071
  f32x16 acc[2][2];
  #pragma unroll
  for (int i = 0; i < 2; ++i)
    #pragma unroll
    for (int j = 0; j < 2; ++j) acc[i][j] = (f32x16)(0.f);

  gemm_acc32<128, 128>(xh, Wcat, Ah, Bh, D, D, D, m0, n0g, acc);

  const int mat = n0g >> 10;              // D = 1024
  const int c0  = n0g & 1023;
  _Float16* C = (mat == 0) ? Qh : (mat == 1) ? Kh : Vh;
  const float* bias = (mat == 0) ? bq : (mat == 1) ? bk : bv;
  gemm_store32<128, 128, true, true, _Float16>(acc, bias, C, D, 1.0f, m0, c0);
}

// mid: blocks 0..543 -> E = QK^T/32 (triangular, TM=128,TN=64);
//      blocks 544..1055 -> VWT = (V@Wo)^T (128x64). 1056 uniform tiles.
__global__ __launch_bounds__(256) void mid_kernel(
    const _Float16* __restrict__ Qh, const _Float16* __restrict__ Kh,
    _Float16* __restrict__ E, const _Float16* __restrict__ WoT,
    const _Float16* __restrict__ Vh, _Float16* __restrict__ VWT,
    int S, int D)
{
  __shared__ _Float16 Ah[128 * BK];
  __shared__ _Float16 Bh[64 * BK];
  const int id = blockIdx.x;
  f32x16 acc[2][1];
  acc[0][0] = (f32x16)(0.f);
  acc[1][0] = (f32x16)(0.f);

  if (id < 544) {                          // QK^T, 272 tiles per batch
    const int z = (id >= 272);
    const int t = id - z * 272;
    int i = (int)((sqrtf(4.f * t + 1.f) - 1.f) * 0.5f);
    while ((i + 1) * (i + 2) <= t) ++i;
    while (i * (i + 1) > t) --i;
    const int j = t - i * (i + 1);         // 0..2i+1
    const int m0 = i * 128, n0 = j * 64;
    gemm_acc32<128, 64>(Qh + (long long)z * S * D, Kh + (long long)z * S * D,
                        Ah, Bh, D, D, D, m0, n0, acc);
    gemm_store32<128, 64, false, false, _Float16>(
        acc, nullptr, E + (long long)z * S * S, S, 0.03125f, m0, n0);
  } else {                                 // V @ Wo, 256 tiles per batch
    const int t = id - 544;
    const int z = t >> 8;
    const int u = t & 255;
    const int m0 = (u >> 5) * 128;         // D rows of Wo^T
    const int n0 = (u & 31) * 64;          // S cols (V rows)
    gemm_acc32<128, 64>(WoT, Vh + (long long)z * S * D,
                        Ah, Bh, D, D, D, m0, n0, acc);
    gemm_store32<128, 64, false, false, _Float16>(
        acc, nullptr, VWT + (long long)z * D * S, S, 1.0f, m0, n0);
  }
}

// out = relu(P @ VW + bo) -> fp32; kend = m0+64 (causal cap); heavy tiles first
__global__ __launch_bounds__(256) void pv_kernel(
    const _Float16* __restrict__ E, const _Float16* __restrict__ VWT,
    const float* __restrict__ bo, float* __restrict__ out, int S, int D)
{
  __shared__ _Float16 Ah[64 * BK];
  __shared__ _Float16 Bh[128 * BK];
  const int z  = blockIdx.z;
  const int m0 = ((int)gridDim.y - 1 - (int)blockIdx.y) * 64;
  const int n0 = blockIdx.x * 128;
  const _Float16* A  = E + (long long)z * S * S;
  const _Float16* BT = VWT + (long long)z * D * S;
  float* C = out + (long long)z * S * D;
  const int kend = m0 + 64;

  f32x16 acc[1][2];
  acc[0][0] = (f32x16)(0.f);
  acc[0][1] = (f32x16)(0.f);

  gemm_acc32<64, 128>(A, BT, Ah, Bh, S, S, kend, m0, n0, acc);
  gemm_store32<64, 128, true, true, float>(acc, bo, C, D, 1.0f, m0, n0);
}

// prep: blocks 0..2047 = x fp32->f16 (8 elems/thread);
//       blocks 2048..3071 = W transpose+convert into Wcat (64x64 tiles)
__global__ __launch_bounds__(256) void prep_kernel(
    const float* __restrict__ x, _Float16* __restrict__ xh,
    const float* __restrict__ W0, const float* __restrict__ W1,
    const float* __restrict__ W2, const float* __restrict__ W3,
    _Float16* __restrict__ Wcat, int D)
{
  const int id = blockIdx.x;
  const int tid = threadIdx.x;
  if (id < 2048) {
    const long long i = ((long long)id * 256 + tid) * 8;
    float4 a = *(const float4*)(x + i);
    float4 b = *(const float4*)(x + i + 4);
    f16x8 o = {(_Float16)a.x, (_Float16)a.y, (_Float16)a.z, (_Float16)a.w,
               (_Float16)b.x, (_Float16)b.y, (_Float16)b.z, (_Float16)b.w};
    *(f16x8*)(xh + i) = o;
    return;
  }
  __shared__ _Float16 t[64][72];
  const int u = id - 2048;
  const int z = u >> 8;
  const int v = u & 255;
  const float* W = (z == 0) ? W0 : (z == 1) ? W1 : (z == 2) ? W2 : W3;
  _Float16* dst = Wcat + (long long)z * D * D;
  const int k0 = (v >> 4) * 64, n0 = (v & 15) * 64;
  #pragma unroll
  for (int it = 0; it < 4; ++it) {
    int idx = tid + it * 256;
    int r = idx >> 4, c4 = (idx & 15) << 2;
    float4 w = *(const float4*)(W + (long long)(k0 + r) * D + n0 + c4);
    t[r][c4 + 0] = (_Float16)w.x; t[r][c4 + 1] = (_Float16)w.y;
    t[r][c4 + 2] = (_Float16)w.z; t[r][c4 + 3] = (_Float16)w.w;
  }
  __syncthreads();
  #pragma unroll
  for (int it = 0; it < 2; ++it) {
    int idx = tid + it * 256;
    int r = idx >> 3, c8 = (idx & 7) << 3;
    f16x8 o;
    #pragma unroll
    for (int j = 0; j < 8; ++j) o[j] = t[c8 + j][r];
    *(f16x8*)(dst + (long long)(n0 + r) * D + k0 + c8) = o;
  }
}

// in-place causal softmax, fp32 math, f16 IO; zeros for j > i
__global__ __launch_bounds__(256) void softmax_causal_h(
    _Float16* __restrict__ E, int S)
{
  const int i = blockIdx.x;
  _Float16* row = E + ((long long)blockIdx.y * S + i) * S;
  const int tid = threadIdx.x;
  const int n = i + 1;
  const int j0 = tid * 8;

  f16x8 hv = *(const f16x8*)(row + j0);
  float vals[8];
  float m = -3.0e38f;
  #pragma unroll
  for (int t = 0; t < 8; ++t) {
    float v = (j0 + t < n) ? (float)hv[t] : -3.0e38f;
    vals[t] = v;
    m = fmaxf(m, v);
  }
  #pragma unroll
  for (int o = 32; o > 0; o >>= 1) m = fmaxf(m, __shfl_down(m, o, 64));

  __shared__ float rmax[4];
  __shared__ float rsum[4];
  const int wave = tid >> 6;
  if ((tid & 63) == 0) rmax[wave] = m;
  __syncthreads();
  m = fmaxf(fmaxf(rmax[0], rmax[1]), fmaxf(rmax[2], rmax[3]));

  float s = 0.f;
  #pragma unroll
  for (int t = 0; t < 8; ++t) {
    float e = (j0 + t < n) ? expf(vals[t] - m) : 0.f;
    vals[t] = e;
    s += e;
  }
  #pragma unroll
  for (int o = 32; o > 0; o >>= 1) s += __shfl_down(s, o, 64);
  if ((tid & 63) == 0) rsum[wave] = s;
  __syncthreads();
  s = rsum[0] + rsum[1] + rsum[2] + rsum[3];

  const float inv = 1.0f / s;
  f16x8 ov;
  #pragma unroll
  for (int t = 0; t < 8; ++t) ov[t] = (_Float16)(vals[t] * inv);
  *(f16x8*)(row + j0) = ov;
}

extern "C" void kernel_launch(void* const* d_in, const int* in_sizes, int n_in,
                              void* d_out, int out_size, void* d_ws, size_t ws_size,
                              hipStream_t stream) {
  const float* x  = (const float*)d_in[0];
  const float* Wq = (const float*)d_in[1];
  const float* bq = (const float*)d_in[2];
  const float* Wk = (const float*)d_in[3];
  const float* bk = (const float*)d_in[4];
  const float* Wv = (const float*)d_in[5];
  const float* bv = (const float*)d_in[6];
  const float* Wo = (const float*)d_in[7];
  const float* bo = (const float*)d_in[8];
  float* out = (float*)d_out;

  const int Bn = 2, S = 2048, D = 1024;
  const int M = Bn * S;                       // 4096
  const size_t MD = (size_t)M * D;            // 4M elems
  const size_t DD = (size_t)D * D;            // 1M
  const size_t SS = (size_t)Bn * S * S;       // 8M

  _Float16* ws   = (_Float16*)d_ws;
  _Float16* xh   = ws;                 // MD
  _Float16* Wcat = xh + MD;            // 4*DD
  _Float16* Qh   = Wcat + 4 * DD;      // MD
  _Float16* Kh   = Qh + MD;            // MD
  _Float16* Vh   = Kh + MD;            // MD
  _Float16* VWT  = Vh + MD;            // MD  ((V@Wo)^T, [D,S] per batch)
  _Float16* E    = VWT + MD;           // SS

  dim3 blk(256);

  prep_kernel<<<dim3(3072), blk, 0, stream>>>(x, xh, Wq, Wk, Wv, Wo, Wcat, D);

  qkv_kernel<<<dim3(3 * D / 128, M / 128), blk, 0, stream>>>(
      xh, Wcat, bq, bk, bv, Qh, Kh, Vh, D);

  mid_kernel<<<dim3(1056), blk, 0, stream>>>(
      Qh, Kh, E, Wcat + 3 * DD, Vh, VWT, S, D);

  softmax_causal_h<<<dim3(S, Bn), blk, 0, stream>>>(E, S);

  pv_kernel<<<dim3(D / 128, S / 64, Bn), blk, 0, stream>>>(
      E, VWT, bo, out, S, D);
}

// Round 13
// 210.994 us; speedup vs baseline: 1.2788x; 1.0097x over previous
//
#include <hip/hip_runtime.h>
#include <math.h>

// Round 13 = round-12 (32x32x16 MFMA core, 213.0 µs) with ONE change:
//   mid's QK^T half moves 128x64 -> 128x128 tiles (272 triangular blocks;
//   halves staging-bytes-per-FLOP to qkv's 0.015 B/F). VW stays 128x64.
//   784 blocks ~ 3.06/CU. 32x32 core keeps VGPR ~36 (r10's 16x16 version
//   died on occupancy at VGPR 72; that objection is gone).
// Accounting note (r12): the two ~43 µs harness poison fills are inside
// dur_us; controllable kernel time is ~118 µs. 5 dispatches; no grid sync.

typedef _Float16 f16x8 __attribute__((ext_vector_type(8)));
typedef float f32x4 __attribute__((ext_vector_type(4)));
typedef float f32x16 __attribute__((ext_vector_type(16)));

#define BK 32   // halves per LDS row (64 B)

__device__ __forceinline__ void gload_lds16(const void* g, void* l) {
  __builtin_amdgcn_global_load_lds(
      (const __attribute__((address_space(1))) void*)g,
      (__attribute__((address_space(3))) void*)l, 16, 0, 0);
}

// Accumulate C-tile (m0,n0) of A @ BT^T over k < kend with 32x32x16 MFMA.
// Wave region (TMp/2 x TNp/2) as (TMp/64 x TNp/64) 32x32 tiles.
// LDS: [row][chunk] chunks of 8 halves; logical chunk c of row r at phys slot
// c ^ ((r>>1)&3); swizzle applied on the global-source side of
// global_load_lds and mirrored in ds_read.
// Operand maps (A and B symmetric => k-permutations cancel):
//   A[m=lane&31][k=8*(lane>>5)+j], B likewise with n in place of m.
template<int TMp, int TNp>
__device__ __forceinline__ void gemm_acc32(
    const _Float16* __restrict__ A, const _Float16* __restrict__ BT,
    _Float16* Ah, _Float16* Bh, int sAr, int sBr, int kend, int m0, int n0,
    f32x16 (&acc)[TMp / 64][TNp / 64])
{
  const int tid  = threadIdx.x;
  const int lane = tid & 63;
  const int wid  = tid >> 6;
  const int wm   = (wid >> 1) * (TMp / 2);
  const int wn   = (wid & 1) * (TNp / 2);
  const int l31  = lane & 31;
  const int hi   = lane >> 5;
  constexpr int MT = TMp / 64;
  constexpr int NT = TNp / 64;
  constexpr int AI = TMp / 64;            // staging instrs per wave
  constexpr int BI = TNp / 64;
  const int r16 = lane >> 2;
  const int swc = ((lane & 3) ^ ((lane >> 3) & 3)) * 8;
  const int arow = wid * (TMp / 4);
  const int brow = wid * (TNp / 4);
  const int s = (l31 >> 1) & 3;           // read-side swizzle key

  for (int k0 = 0; k0 < kend; k0 += BK) {
    #pragma unroll
    for (int t = 0; t < AI; ++t)
      gload_lds16(A + (long long)(m0 + arow + t * 16 + r16) * sAr + k0 + swc,
                  Ah + (arow + t * 16) * BK);
    #pragma unroll
    for (int t = 0; t < BI; ++t)
      gload_lds16(BT + (long long)(n0 + brow + t * 16 + r16) * sBr + k0 + swc,
                  Bh + (brow + t * 16) * BK);
    __syncthreads();

    #pragma unroll
    for (int ks = 0; ks < 2; ++ks) {
      const int ch = ((ks * 2 + hi) ^ s) * 8;   // swizzled slot
      f16x8 af[MT], bf[NT];
      #pragma unroll
      for (int mt = 0; mt < MT; ++mt)
        af[mt] = *(const f16x8*)(Ah + (wm + mt * 32 + l31) * BK + ch);
      #pragma unroll
      for (int nt = 0; nt < NT; ++nt)
        bf[nt] = *(const f16x8*)(Bh + (wn + nt * 32 + l31) * BK + ch);
      #pragma unroll
      for (int mt = 0; mt < MT; ++mt)
        #pragma unroll
        for (int nt = 0; nt < NT; ++nt)
          acc[mt][nt] = __builtin_amdgcn_mfma_f32_32x32x16_f16(
              af[mt], bf[nt], acc[mt][nt], 0, 0, 0);
    }
    __syncthreads();
  }
}

// Epilogue for 32x32 C/D (HW-verified m74/m101, dtype-independent):
//   col = lane&31, row = (reg&3) + 8*(reg>>2) + 4*(lane>>5).
template<int TMp, int TNp, bool RELU, bool HAS_BIAS, typename OT>
__device__ __forceinline__ void gemm_store32(
    f32x16 (&acc)[TMp / 64][TNp / 64], const float* __restrict__ bias,
    OT* __restrict__ C, int Nout, float scale, int m0, int n0)
{
  const int tid  = threadIdx.x;
  const int lane = tid & 63;
  const int wid  = tid >> 6;
  const int wm   = (wid >> 1) * (TMp / 2);
  const int wn   = (wid & 1) * (TNp / 2);
  const int l31  = lane & 31;
  const int hi   = lane >> 5;
  constexpr int MT = TMp / 64;
  constexpr int NT = TNp / 64;

  float bvals[NT];
  if (HAS_BIAS) {
    #pragma unroll
    for (int nt = 0; nt < NT; ++nt)
      bvals[nt] = bias[n0 + wn + nt * 32 + l31];
  }
  #pragma unroll
  for (int mt = 0; mt < MT; ++mt) {
    #pragma unroll
    for (int nt = 0; nt < NT; ++nt) {
      const int col = n0 + wn + nt * 32 + l31;
      const int rbase = m0 + wm + mt * 32 + 4 * hi;
      #pragma unroll
      for (int r = 0; r < 16; ++r) {
        const int row = rbase + (r & 3) + 8 * (r >> 2);
        float v = acc[mt][nt][r] * scale;
        if (HAS_BIAS) v += bvals[nt];
        if (RELU) v = fmaxf(v, 0.f);
        C[(long long)row * Nout + col] = (OT)v;
      }
    }
  }
}

// fused QKV: relu(x @ W{q,k,v} + b) -> f16; Wcat = [Wq^T;Wk^T;Wv^T;Wo^T]
__global__ __launch_bounds__(256) void qkv_kernel(
    const _Float16* __restrict__ xh, const _Float16* __restrict__ Wcat,
    const float* __restrict__ bq, const float* __restrict__ bk,
    const float* __restrict__ bv,
    _Float16* __restrict__ Qh, _Float16* __restrict__ Kh,
    _Float16* __restrict__ Vh, int D)
{
  __shared__ _Float16 Ah[128 * BK];
  __shared__ _Float16 Bh[128 * BK];
  const int m0  = blockIdx.y * 128;
  const int n0g = blockIdx.x * 128;       // 0..3071
  f32x16 acc[2][2];
  #pragma unroll
  for (int i = 0; i < 2; ++i)
    #pragma unroll
    for (int j = 0; j < 2; ++j) acc[i][j] = (f32x16)(0.f);

  gemm_acc32<128, 128>(xh, Wcat, Ah, Bh, D, D, D, m0, n0g, acc);

  const int mat = n0g >> 10;              // D = 1024
  const int c0  = n0g & 1023;
  _Float16* C = (mat == 0) ? Qh : (mat == 1) ? Kh : Vh;
  const float* bias = (mat == 0) ? bq : (mat == 1) ? bk : bv;
  gemm_store32<128, 128, true, true, _Float16>(acc, bias, C, D, 1.0f, m0, c0);
}

// mid: blocks 0..271   -> E = QK^T/32, 128x128 triangular tiles (136/batch;
//                         diagonal upper junk never read by softmax);
//      blocks 272..783 -> VWT = (V@Wo)^T, 128x64 tiles (256/batch).
__global__ __launch_bounds__(256) void mid_kernel(
    const _Float16* __restrict__ Qh, const _Float16* __restrict__ Kh,
    _Float16* __restrict__ E, const _Float16* __restrict__ WoT,
    const _Float16* __restrict__ Vh, _Float16* __restrict__ VWT,
    int S, int D)
{
  __shared__ _Float16 Ah[128 * BK];
  __shared__ _Float16 Bh[128 * BK];
  const int id = blockIdx.x;
  if (id < 272) {                          // QK^T, 136 tiles per batch (j<=i)
    const int z = (id >= 136);
    const int t = id - z * 136;
    int i = (int)((sqrtf(8.f * t + 1.f) - 1.f) * 0.5f);
    while ((i + 1) * (i + 2) / 2 <= t) ++i;
    while (i * (i + 1) / 2 > t) --i;
    const int j = t - i * (i + 1) / 2;     // 0..i
    const int m0 = i * 128, n0 = j * 128;
    f32x16 acc[2][2];
    #pragma unroll
    for (int a = 0; a < 2; ++a)
      #pragma unroll
      for (int b = 0; b < 2; ++b) acc[a][b] = (f32x16)(0.f);
    gemm_acc32<128, 128>(Qh + (long long)z * S * D, Kh + (long long)z * S * D,
                         Ah, Bh, D, D, D, m0, n0, acc);
    gemm_store32<128, 128, false, false, _Float16>(
        acc, nullptr, E + (long long)z * S * S, S, 0.03125f, m0, n0);
  } else {                                 // V @ Wo, 256 tiles per batch
    const int t = id - 272;
    const int z = t >> 8;
    const int u = t & 255;
    const int m0 = (u >> 5) * 128;         // D rows of Wo^T
    const int n0 = (u & 31) * 64;          // S cols (V rows)
    f32x16 acc[2][1];
    acc[0][0] = (f32x16)(0.f);
    acc[1][0] = (f32x16)(0.f);
    gemm_acc32<128, 64>(WoT, Vh + (long long)z * S * D,
                        Ah, Bh, D, D, D, m0, n0, acc);
    gemm_store32<128, 64, false, false, _Float16>(
        acc, nullptr, VWT + (long long)z * D * S, S, 1.0f, m0, n0);
  }
}

// out = relu(P @ VW + bo) -> fp32; kend = m0+64 (causal cap); heavy tiles first
__global__ __launch_bounds__(256) void pv_kernel(
    const _Float16* __restrict__ E, const _Float16* __restrict__ VWT,
    const float* __restrict__ bo, float* __restrict__ out, int S, int D)
{
  __shared__ _Float16 Ah[64 * BK];
  __shared__ _Float16 Bh[128 * BK];
  const int z  = blockIdx.z;
  const int m0 = ((int)gridDim.y - 1 - (int)blockIdx.y) * 64;
  const int n0 = blockIdx.x * 128;
  const _Float16* A  = E + (long long)z * S * S;
  const _Float16* BT = VWT + (long long)z * D * S;
  float* C = out + (long long)z * S * D;
  const int kend = m0 + 64;

  f32x16 acc[1][2];
  acc[0][0] = (f32x16)(0.f);
  acc[0][1] = (f32x16)(0.f);

  gemm_acc32<64, 128>(A, BT, Ah, Bh, S, S, kend, m0, n0, acc);
  gemm_store32<64, 128, true, true, float>(acc, bo, C, D, 1.0f, m0, n0);
}

// prep: blocks 0..2047 = x fp32->f16 (8 elems/thread);
//       blocks 2048..3071 = W transpose+convert into Wcat (64x64 tiles)
__global__ __launch_bounds__(256) void prep_kernel(
    const float* __restrict__ x, _Float16* __restrict__ xh,
    const float* __restrict__ W0, const float* __restrict__ W1,
    const float* __restrict__ W2, const float* __restrict__ W3,
    _Float16* __restrict__ Wcat, int D)
{
  const int id = blockIdx.x;
  const int tid = threadIdx.x;
  if (id < 2048) {
    const long long i = ((long long)id * 256 + tid) * 8;
    float4 a = *(const float4*)(x + i);
    float4 b = *(const float4*)(x + i + 4);
    f16x8 o = {(_Float16)a.x, (_Float16)a.y, (_Float16)a.z, (_Float16)a.w,
               (_Float16)b.x, (_Float16)b.y, (_Float16)b.z, (_Float16)b.w};
    *(f16x8*)(xh + i) = o;
    return;
  }
  __shared__ _Float16 t[64][72];
  const int u = id - 2048;
  const int z = u >> 8;
  const int v = u & 255;
  const float* W = (z == 0) ? W0 : (z == 1) ? W1 : (z == 2) ? W2 : W3;
  _Float16* dst = Wcat + (long long)z * D * D;
  const int k0 = (v >> 4) * 64, n0 = (v & 15) * 64;
  #pragma unroll
  for (int it = 0; it < 4; ++it) {
    int idx = tid + it * 256;
    int r = idx >> 4, c4 = (idx & 15) << 2;
    float4 w = *(const float4*)(W + (long long)(k0 + r) * D + n0 + c4);
    t[r][c4 + 0] = (_Float16)w.x; t[r][c4 + 1] = (_Float16)w.y;
    t[r][c4 + 2] = (_Float16)w.z; t[r][c4 + 3] = (_Float16)w.w;
  }
  __syncthreads();
  #pragma unroll
  for (int it = 0; it < 2; ++it) {
    int idx = tid + it * 256;
    int r = idx >> 3, c8 = (idx & 7) << 3;
    f16x8 o;
    #pragma unroll
    for (int j = 0; j < 8; ++j) o[j] = t[c8 + j][r];
    *(f16x8*)(dst + (long long)(n0 + r) * D + k0 + c8) = o;
  }
}

// in-place causal softmax, fp32 math, f16 IO; zeros for j > i
__global__ __launch_bounds__(256) void softmax_causal_h(
    _Float16* __restrict__ E, int S)
{
  const int i = blockIdx.x;
  _Float16* row = E + ((long long)blockIdx.y * S + i) * S;
  const int tid = threadIdx.x;
  const int n = i + 1;
  const int j0 = tid * 8;

  f16x8 hv = *(const f16x8*)(row + j0);
  float vals[8];
  float m = -3.0e38f;
  #pragma unroll
  for (int t = 0; t < 8; ++t) {
    float v = (j0 + t < n) ? (float)hv[t] : -3.0e38f;
    vals[t] = v;
    m = fmaxf(m, v);
  }
  #pragma unroll
  for (int o = 32; o > 0; o >>= 1) m = fmaxf(m, __shfl_down(m, o, 64));

  __shared__ float rmax[4];
  __shared__ float rsum[4];
  const int wave = tid >> 6;
  if ((tid & 63) == 0) rmax[wave] = m;
  __syncthreads();
  m = fmaxf(fmaxf(rmax[0], rmax[1]), fmaxf(rmax[2], rmax[3]));

  float s = 0.f;
  #pragma unroll
  for (int t = 0; t < 8; ++t) {
    float e = (j0 + t < n) ? expf(vals[t] - m) : 0.f;
    vals[t] = e;
    s += e;
  }
  #pragma unroll
  for (int o = 32; o > 0; o >>= 1) s += __shfl_down(s, o, 64);
  if ((tid & 63) == 0) rsum[wave] = s;
  __syncthreads();
  s = rsum[0] + rsum[1] + rsum[2] + rsum[3];

  const float inv = 1.0f / s;
  f16x8 ov;
  #pragma unroll
  for (int t = 0; t < 8; ++t) ov[t] = (_Float16)(vals[t] * inv);
  *(f16x8*)(row + j0) = ov;
}

extern "C" void kernel_launch(void* const* d_in, const int* in_sizes, int n_in,
                              void* d_out, int out_size, void* d_ws, size_t ws_size,
                              hipStream_t stream) {
  const float* x  = (const float*)d_in[0];
  const float* Wq = (const float*)d_in[1];
  const float* bq = (const float*)d_in[2];
  const float* Wk = (const float*)d_in[3];
  const float* bk = (const float*)d_in[4];
  const float* Wv = (const float*)d_in[5];
  const float* bv = (const float*)d_in[6];
  const float* Wo = (const float*)d_in[7];
  const float* bo = (const float*)d_in[8];
  float* out = (float*)d_out;

  const int Bn = 2, S = 2048, D = 1024;
  const int M = Bn * S;                       // 4096
  const size_t MD = (size_t)M * D;            // 4M elems
  const size_t DD = (size_t)D * D;            // 1M
  const size_t SS = (size_t)Bn * S * S;       // 8M

  _Float16* ws   = (_Float16*)d_ws;
  _Float16* xh   = ws;                 // MD
  _Float16* Wcat = xh + MD;            // 4*DD
  _Float16* Qh   = Wcat + 4 * DD;      // MD
  _Float16* Kh   = Qh + MD;            // MD
  _Float16* Vh   = Kh + MD;            // MD
  _Float16* VWT  = Vh + MD;            // MD  ((V@Wo)^T, [D,S] per batch)
  _Float16* E    = VWT + MD;           // SS

  dim3 blk(256);

  prep_kernel<<<dim3(3072), blk, 0, stream>>>(x, xh, Wq, Wk, Wv, Wo, Wcat, D);

  qkv_kernel<<<dim3(3 * D / 128, M / 128), blk, 0, stream>>>(
      xh, Wcat, bq, bk, bv, Qh, Kh, Vh, D);

  mid_kernel<<<dim3(784), blk, 0, stream>>>(
      Qh, Kh, E, Wcat + 3 * DD, Vh, VWT, S, D);

  softmax_causal_h<<<dim3(S, Bn), blk, 0, stream>>>(E, S);

  pv_kernel<<<dim3(D / 128, S / 64, Bn), blk, 0, stream>>>(
      E, VWT, bo, out, S, D);
}